// Round 1
// baseline (632.734 us; speedup 1.0000x reference)
//
#include <hip/hip_runtime.h>
#include <float.h>
#include <math.h>

// Problem constants (fixed by the reference)
#define NB 1024      // number of graphs B
#define HD 64        // feature dim H
#define NSTEPS 5
#define PROJ_D 128

__device__ __forceinline__ float sigmoidf_(float x) {
    return 1.0f / (1.0f + __expf(-x));
}

// ---------------- init: zero LSTM/Set2Set state ----------------
__global__ void init_state_kernel(float* __restrict__ q_star,
                                  float* __restrict__ h,
                                  float* __restrict__ c) {
    int i = blockIdx.x * blockDim.x + threadIdx.x;
    if (i < NB * 2 * HD) q_star[i] = 0.0f;
    if (i < NB * HD) { h[i] = 0.0f; c[i] = 0.0f; }
}

// ---------------- segment boundaries from sorted batch ----------------
// seg_start[b] = first index i with batch[i] >= b ; seg_start[NB] = n
__global__ void seg_bounds_kernel(const int* __restrict__ batch,
                                  int* __restrict__ seg_start, int n) {
    int i = blockIdx.x * blockDim.x + threadIdx.x;
    if (i >= n) return;
    int b = batch[i];
    if (i == 0) {
        for (int j = 0; j <= b; ++j) seg_start[j] = 0;
    } else {
        int pb = batch[i - 1];
        for (int j = pb + 1; j <= b; ++j) seg_start[j] = i;
    }
    if (i == n - 1) {
        for (int j = b + 1; j <= NB; ++j) seg_start[j] = n;
    }
}

// ---------------- LSTM cell: gates = q_star@W_ih^T + b_ih + h@W_hh^T + b_hh ----------------
// grid = NB/8 blocks, 256 threads; each block handles 8 graphs, thread j = gate j.
__global__ void lstm_kernel(const float* __restrict__ W_ih,  // [256,128]
                            const float* __restrict__ W_hh,  // [256,64]
                            const float* __restrict__ b_ih,  // [256]
                            const float* __restrict__ b_hh,  // [256]
                            float* __restrict__ q_star,      // [NB,128]
                            float* __restrict__ h,           // [NB,64]
                            float* __restrict__ c) {         // [NB,64]
    const int G = 8;
    int g0 = blockIdx.x * G;
    __shared__ float s_qs[G][128];
    __shared__ float s_h[G][64];
    __shared__ float s_gates[G][256];
    int tid = threadIdx.x;

    for (int idx = tid; idx < G * 128; idx += 256) {
        int g = idx >> 7, k = idx & 127;
        s_qs[g][k] = q_star[(g0 + g) * 128 + k];
    }
    for (int idx = tid; idx < G * 64; idx += 256) {
        int g = idx >> 6, k = idx & 63;
        s_h[g][k] = h[(g0 + g) * 64 + k];
    }
    __syncthreads();

    int j = tid;  // gate row 0..255
    float acc[G];
    float bias = b_ih[j] + b_hh[j];
#pragma unroll
    for (int g = 0; g < G; ++g) acc[g] = bias;
    const float* wih = W_ih + j * 128;
    for (int k = 0; k < 128; ++k) {
        float w = wih[k];
#pragma unroll
        for (int g = 0; g < G; ++g) acc[g] = fmaf(w, s_qs[g][k], acc[g]);
    }
    const float* whh = W_hh + j * 64;
    for (int k = 0; k < 64; ++k) {
        float w = whh[k];
#pragma unroll
        for (int g = 0; g < G; ++g) acc[g] = fmaf(w, s_h[g][k], acc[g]);
    }
#pragma unroll
    for (int g = 0; g < G; ++g) s_gates[g][j] = acc[g];
    __syncthreads();

    // update c, h; write h into q_star[:,0:64]
    for (int idx = tid; idx < G * 64; idx += 256) {
        int g = idx >> 6, jj = idx & 63;
        int gb = g0 + g;
        float ig = sigmoidf_(s_gates[g][jj]);
        float fg = sigmoidf_(s_gates[g][jj + 64]);
        float gg = tanhf(s_gates[g][jj + 128]);
        float og = sigmoidf_(s_gates[g][jj + 192]);
        float cn = fmaf(fg, c[gb * 64 + jj], ig * gg);
        float hn = og * tanhf(cn);
        c[gb * 64 + jj] = cn;
        h[gb * 64 + jj] = hn;
        q_star[gb * 128 + jj] = hn;
    }
}

// ---------------- fused segment attention (online softmax, single pass) ----------------
// One block per graph. 256 threads = 4 waves; lane-quad owns a node, lane owns 16 features.
__global__ __launch_bounds__(256) void attn_kernel(const float* __restrict__ x,
                                                   const int* __restrict__ seg_start,
                                                   float* __restrict__ q_star) {
    int b = blockIdx.x;
    int s = seg_start[b], e = seg_start[b + 1];
    int tid = threadIdx.x;
    int lane = tid & 63;
    int wave = tid >> 6;      // 0..3
    int quad = lane >> 2;     // 0..15
    int p = lane & 3;         // feature part: features [p*16, p*16+16)

    // q = h for this graph (q_star[b][0:64])
    float q[16];
    const float* qsrc = q_star + b * 128 + p * 16;
#pragma unroll
    for (int k = 0; k < 16; ++k) q[k] = qsrc[k];

    float m = -FLT_MAX, sum = 0.0f;
    float r[16];
#pragma unroll
    for (int k = 0; k < 16; ++k) r[k] = 0.0f;

    for (int base = s; base < e; base += 64) {
        int node = base + wave * 16 + quad;
        bool valid = node < e;
        float xv[16];
        if (valid) {
            const float4* xp = (const float4*)(x + (size_t)node * 64 + p * 16);
            float4 a0 = xp[0], a1 = xp[1], a2 = xp[2], a3 = xp[3];
            xv[0] = a0.x; xv[1] = a0.y; xv[2] = a0.z; xv[3] = a0.w;
            xv[4] = a1.x; xv[5] = a1.y; xv[6] = a1.z; xv[7] = a1.w;
            xv[8] = a2.x; xv[9] = a2.y; xv[10] = a2.z; xv[11] = a2.w;
            xv[12] = a3.x; xv[13] = a3.y; xv[14] = a3.z; xv[15] = a3.w;
        } else {
#pragma unroll
            for (int k = 0; k < 16; ++k) xv[k] = 0.0f;
        }
        float dot = 0.0f;
#pragma unroll
        for (int k = 0; k < 16; ++k) dot = fmaf(xv[k], q[k], dot);
        // reduce within quad (all 4 lanes share the node)
        dot += __shfl_xor(dot, 1);
        dot += __shfl_xor(dot, 2);
        float eeff = valid ? dot : -FLT_MAX;
        float nm = fmaxf(m, eeff);
        float scale = __expf(m - nm);          // ==1 when m==nm (incl. both -FLT_MAX)
        float w = valid ? __expf(eeff - nm) : 0.0f;
        sum = fmaf(sum, scale, w);
#pragma unroll
        for (int k = 0; k < 16; ++k) r[k] = fmaf(r[k], scale, w * xv[k]);
        m = nm;
    }

    // merge across the 16 quads of this wave (lanes with equal p hold same features)
#pragma unroll
    for (int off = 4; off < 64; off <<= 1) {
        float om = __shfl_xor(m, off);
        float os = __shfl_xor(sum, off);
        float orr[16];
#pragma unroll
        for (int k = 0; k < 16; ++k) orr[k] = __shfl_xor(r[k], off);
        float nm = fmaxf(m, om);
        float sc1 = __expf(m - nm);
        float sc2 = __expf(om - nm);
        sum = sum * sc1 + os * sc2;
#pragma unroll
        for (int k = 0; k < 16; ++k) r[k] = r[k] * sc1 + orr[k] * sc2;
        m = nm;
    }

    // cross-wave merge via LDS
    __shared__ float lm[4], ls[4], lr[4][64];
    if (lane < 4) {
        if (lane == 0) { lm[wave] = m; ls[wave] = sum; }
#pragma unroll
        for (int k = 0; k < 16; ++k) lr[wave][lane * 16 + k] = r[k];
    }
    __syncthreads();
    if (tid < 64) {
        float M = fmaxf(fmaxf(lm[0], lm[1]), fmaxf(lm[2], lm[3]));
        float w0 = __expf(lm[0] - M), w1 = __expf(lm[1] - M);
        float w2 = __expf(lm[2] - M), w3 = __expf(lm[3] - M);
        float S = ls[0] * w0 + ls[1] * w1 + ls[2] * w2 + ls[3] * w3;
        float rf = lr[0][tid] * w0 + lr[1][tid] * w1 + lr[2][tid] * w2 + lr[3][tid] * w3;
        float denom = fmaxf(S, 1e-16f);
        q_star[b * 128 + 64 + tid] = rf / denom;  // r into q_star[:,64:128]
    }
}

// ---------------- final MLP: relu(q_star@W1^T+b1)@W2^T+b2 ----------------
__global__ void mlp_kernel(const float* __restrict__ q_star,
                           const float* __restrict__ W1,  // [256,128]
                           const float* __restrict__ b1,  // [256]
                           const float* __restrict__ W2,  // [128,256]
                           const float* __restrict__ b2,  // [128]
                           float* __restrict__ out) {     // [NB,128]
    int b = blockIdx.x;
    __shared__ float qs[128];
    __shared__ float hid[256];
    int tid = threadIdx.x;
    if (tid < 128) qs[tid] = q_star[b * 128 + tid];
    __syncthreads();
    float acc = b1[tid];
    const float* w = W1 + tid * 128;
    for (int k = 0; k < 128; ++k) acc = fmaf(w[k], qs[k], acc);
    hid[tid] = fmaxf(acc, 0.0f);
    __syncthreads();
    if (tid < 128) {
        float acc2 = b2[tid];
        const float* w2 = W2 + tid * 256;
        for (int k = 0; k < 256; ++k) acc2 = fmaf(w2[k], hid[k], acc2);
        out[b * 128 + tid] = acc2;
    }
}

extern "C" void kernel_launch(void* const* d_in, const int* in_sizes, int n_in,
                              void* d_out, int out_size, void* d_ws, size_t ws_size,
                              hipStream_t stream) {
    const float* x    = (const float*)d_in[0];   // [N,64]
    const int*   batch= (const int*)d_in[1];     // [N] sorted
    const float* W_ih = (const float*)d_in[2];   // [256,128]
    const float* W_hh = (const float*)d_in[3];   // [256,64]
    const float* b_ih = (const float*)d_in[4];
    const float* b_hh = (const float*)d_in[5];
    const float* W1   = (const float*)d_in[6];   // [256,128]
    const float* b1   = (const float*)d_in[7];
    const float* W2   = (const float*)d_in[8];   // [128,256]
    const float* b2   = (const float*)d_in[9];
    float* out = (float*)d_out;
    const int N = in_sizes[1];

    // workspace layout
    float* q_star = (float*)d_ws;                 // NB*128
    float* h      = q_star + NB * 128;            // NB*64
    float* c      = h + NB * 64;                  // NB*64
    int*   seg    = (int*)(c + NB * 64);          // NB+1

    // init state (ws is re-poisoned before every call)
    init_state_kernel<<<(NB * 2 * HD + 255) / 256, 256, 0, stream>>>(q_star, h, c);
    seg_bounds_kernel<<<(N + 255) / 256, 256, 0, stream>>>(batch, seg, N);

    for (int step = 0; step < NSTEPS; ++step) {
        lstm_kernel<<<NB / 8, 256, 0, stream>>>(W_ih, W_hh, b_ih, b_hh, q_star, h, c);
        attn_kernel<<<NB, 256, 0, stream>>>(x, seg, q_star);
    }
    mlp_kernel<<<NB, 256, 0, stream>>>(q_star, W1, b1, W2, b2, out);
}

// Round 2
// 618.879 us; speedup vs baseline: 1.0224x; 1.0224x over previous
//
#include <hip/hip_runtime.h>
#include <float.h>
#include <math.h>

// Problem constants (fixed by the reference)
#define NB 1024      // number of graphs B
#define HD 64        // feature dim H
#define NSTEPS 5
#define SPLIT 4      // blocks per graph segment in attention

__device__ __forceinline__ float sigmoidf_(float x) {
    return 1.0f / (1.0f + __expf(-x));
}

// ---------------- segment boundaries from sorted batch ----------------
// seg_start[b] = first index i with batch[i] >= b ; seg_start[NB] = n
__global__ void seg_bounds_kernel(const int* __restrict__ batch,
                                  int* __restrict__ seg_start, int n) {
    int i = blockIdx.x * blockDim.x + threadIdx.x;
    if (i >= n) return;
    int b = batch[i];
    if (i == 0) {
        for (int j = 0; j <= b; ++j) seg_start[j] = 0;
    } else {
        int pb = batch[i - 1];
        for (int j = pb + 1; j <= b; ++j) seg_start[j] = i;
    }
    if (i == n - 1) {
        for (int j = b + 1; j <= NB; ++j) seg_start[j] = n;
    }
}

// ---------------- LSTM cell, fused with merge of previous step's attention partials ----------------
// grid = NB/8 blocks, 256 threads; each block handles 8 graphs, thread j = gate row j.
// gates = [h_prev, r_prev] @ W_ih^T + b_ih + h_prev @ W_hh^T + b_hh
__global__ void lstm_kernel(const float* __restrict__ W_ih,  // [256,128]
                            const float* __restrict__ W_hh,  // [256,64]
                            const float* __restrict__ b_ih,  // [256]
                            const float* __restrict__ b_hh,  // [256]
                            const float* __restrict__ pm,    // [NB*SPLIT]
                            const float* __restrict__ ps,    // [NB*SPLIT]
                            const float* __restrict__ pr,    // [NB*SPLIT,64]
                            float* __restrict__ h,           // [NB,64]
                            float* __restrict__ c,           // [NB,64]
                            int first) {
    const int G = 8;
    int g0 = blockIdx.x * G;
    __shared__ float s_qs[G][128];    // [h_prev | r_prev]
    __shared__ float s_gates[G][256];
    int tid = threadIdx.x;

    if (!first) {
        // low half: h_prev
        for (int idx = tid; idx < G * 64; idx += 256) {
            int g = idx >> 6, k = idx & 63;
            s_qs[g][k] = h[(g0 + g) * 64 + k];
        }
        // high half: merge SPLIT partials -> r_prev
        for (int idx = tid; idx < G * 64; idx += 256) {
            int g = idx >> 6, k = idx & 63;
            int b = g0 + g;
            float m0 = pm[b * SPLIT + 0], m1 = pm[b * SPLIT + 1];
            float m2 = pm[b * SPLIT + 2], m3 = pm[b * SPLIT + 3];
            float M = fmaxf(fmaxf(m0, m1), fmaxf(m2, m3));
            float w0 = __expf(m0 - M), w1 = __expf(m1 - M);
            float w2 = __expf(m2 - M), w3 = __expf(m3 - M);
            float S = ps[b * SPLIT + 0] * w0 + ps[b * SPLIT + 1] * w1
                    + ps[b * SPLIT + 2] * w2 + ps[b * SPLIT + 3] * w3;
            float rf = pr[(b * SPLIT + 0) * 64 + k] * w0
                     + pr[(b * SPLIT + 1) * 64 + k] * w1
                     + pr[(b * SPLIT + 2) * 64 + k] * w2
                     + pr[(b * SPLIT + 3) * 64 + k] * w3;
            s_qs[g][64 + k] = rf / fmaxf(S, 1e-16f);
        }
        __syncthreads();
    }

    int j = tid;  // gate row 0..255
    float acc[G];
    float bias = b_ih[j] + b_hh[j];
#pragma unroll
    for (int g = 0; g < G; ++g) acc[g] = bias;

    if (!first) {
        const float4* wih = (const float4*)(W_ih + j * 128);
#pragma unroll 4
        for (int k4 = 0; k4 < 32; ++k4) {
            float4 w = wih[k4];
#pragma unroll
            for (int g = 0; g < G; ++g) {
                acc[g] = fmaf(w.x, s_qs[g][k4 * 4 + 0], acc[g]);
                acc[g] = fmaf(w.y, s_qs[g][k4 * 4 + 1], acc[g]);
                acc[g] = fmaf(w.z, s_qs[g][k4 * 4 + 2], acc[g]);
                acc[g] = fmaf(w.w, s_qs[g][k4 * 4 + 3], acc[g]);
            }
        }
        const float4* whh = (const float4*)(W_hh + j * 64);
#pragma unroll 4
        for (int k4 = 0; k4 < 16; ++k4) {
            float4 w = whh[k4];
#pragma unroll
            for (int g = 0; g < G; ++g) {
                // hidden state = h_prev = s_qs[g][0:64]
                acc[g] = fmaf(w.x, s_qs[g][k4 * 4 + 0], acc[g]);
                acc[g] = fmaf(w.y, s_qs[g][k4 * 4 + 1], acc[g]);
                acc[g] = fmaf(w.z, s_qs[g][k4 * 4 + 2], acc[g]);
                acc[g] = fmaf(w.w, s_qs[g][k4 * 4 + 3], acc[g]);
            }
        }
    }
#pragma unroll
    for (int g = 0; g < G; ++g) s_gates[g][j] = acc[g];
    __syncthreads();

    for (int idx = tid; idx < G * 64; idx += 256) {
        int g = idx >> 6, jj = idx & 63;
        int gb = g0 + g;
        float ig = sigmoidf_(s_gates[g][jj]);
        float fg = sigmoidf_(s_gates[g][jj + 64]);
        float gg = tanhf(s_gates[g][jj + 128]);
        float og = sigmoidf_(s_gates[g][jj + 192]);
        float cprev = first ? 0.0f : c[gb * 64 + jj];
        float cn = fmaf(fg, cprev, ig * gg);
        float hn = og * tanhf(cn);
        c[gb * 64 + jj] = cn;
        h[gb * 64 + jj] = hn;
    }
}

// ---------------- fused segment attention (online softmax, single pass) ----------------
// grid = NB*SPLIT blocks; block (b,slice) handles its slice of graph b's segment.
// 256 threads = 4 waves; lane-quad owns a node, lane owns 16 features.
// Writes UNNORMALIZED partials (m, s, r[64]) to ws.
__global__ __launch_bounds__(256) void attn_kernel(const float* __restrict__ x,
                                                   const int* __restrict__ seg_start,
                                                   const float* __restrict__ h,
                                                   float* __restrict__ pm,
                                                   float* __restrict__ ps,
                                                   float* __restrict__ pr) {
    int bs = blockIdx.x;
    int b = bs >> 2;            // SPLIT == 4
    int slice = bs & (SPLIT - 1);
    int s0 = seg_start[b], e0 = seg_start[b + 1];
    int len = e0 - s0;
    int s = s0 + (int)(((long long)len * slice) >> 2);
    int e = s0 + (int)(((long long)len * (slice + 1)) >> 2);

    int tid = threadIdx.x;
    int lane = tid & 63;
    int wave = tid >> 6;      // 0..3
    int quad = lane >> 2;     // 0..15
    int p = lane & 3;         // feature part: features [p*16, p*16+16)

    // q = h for this graph
    float q[16];
    const float* qsrc = h + b * 64 + p * 16;
#pragma unroll
    for (int k = 0; k < 16; ++k) q[k] = qsrc[k];

    float m = -FLT_MAX, sum = 0.0f;
    float r[16];
#pragma unroll
    for (int k = 0; k < 16; ++k) r[k] = 0.0f;

    // branch-free loads: clamp node to e-1, mask the contribution.
    for (int base = s; base < e; base += 64) {
        int node = base + wave * 16 + quad;
        bool valid = node < e;
        int nc = valid ? node : (e - 1);
        const float4* xp = (const float4*)(x + (size_t)nc * 64 + p * 16);
        float4 a0 = xp[0], a1 = xp[1], a2 = xp[2], a3 = xp[3];
        float xv[16];
        xv[0] = a0.x; xv[1] = a0.y; xv[2] = a0.z; xv[3] = a0.w;
        xv[4] = a1.x; xv[5] = a1.y; xv[6] = a1.z; xv[7] = a1.w;
        xv[8] = a2.x; xv[9] = a2.y; xv[10] = a2.z; xv[11] = a2.w;
        xv[12] = a3.x; xv[13] = a3.y; xv[14] = a3.z; xv[15] = a3.w;

        float dot = 0.0f;
#pragma unroll
        for (int k = 0; k < 16; ++k) dot = fmaf(xv[k], q[k], dot);
        dot += __shfl_xor(dot, 1);
        dot += __shfl_xor(dot, 2);

        float eeff = valid ? dot : -FLT_MAX;
        float nm = fmaxf(m, eeff);
        float scale = __expf(m - nm);            // ==1 when m==nm (incl. both -FLT_MAX)
        float w = valid ? __expf(eeff - nm) : 0.0f;
        sum = fmaf(sum, scale, w);
#pragma unroll
        for (int k = 0; k < 16; ++k) r[k] = fmaf(r[k], scale, w * xv[k]);
        m = nm;
    }

    // merge across the 16 quads of this wave
#pragma unroll
    for (int off = 4; off < 64; off <<= 1) {
        float om = __shfl_xor(m, off);
        float os = __shfl_xor(sum, off);
        float orr[16];
#pragma unroll
        for (int k = 0; k < 16; ++k) orr[k] = __shfl_xor(r[k], off);
        float nm = fmaxf(m, om);
        float sc1 = __expf(m - nm);
        float sc2 = __expf(om - nm);
        sum = sum * sc1 + os * sc2;
#pragma unroll
        for (int k = 0; k < 16; ++k) r[k] = r[k] * sc1 + orr[k] * sc2;
        m = nm;
    }

    // cross-wave merge via LDS; write UNNORMALIZED partials
    __shared__ float lm[4], ls[4], lr[4][64];
    if (lane < 4) {
        if (lane == 0) { lm[wave] = m; ls[wave] = sum; }
#pragma unroll
        for (int k = 0; k < 16; ++k) lr[wave][lane * 16 + k] = r[k];
    }
    __syncthreads();
    if (tid < 64) {
        float M = fmaxf(fmaxf(lm[0], lm[1]), fmaxf(lm[2], lm[3]));
        float w0 = __expf(lm[0] - M), w1 = __expf(lm[1] - M);
        float w2 = __expf(lm[2] - M), w3 = __expf(lm[3] - M);
        float S = ls[0] * w0 + ls[1] * w1 + ls[2] * w2 + ls[3] * w3;
        float rf = lr[0][tid] * w0 + lr[1][tid] * w1 + lr[2][tid] * w2 + lr[3][tid] * w3;
        if (tid == 0) { pm[bs] = M; ps[bs] = S; }
        pr[bs * 64 + tid] = rf;
    }
}

// ---------------- final: merge last partials, build q_star, MLP ----------------
__global__ void mlp_kernel(const float* __restrict__ h,
                           const float* __restrict__ pm,
                           const float* __restrict__ ps,
                           const float* __restrict__ pr,
                           const float* __restrict__ W1,  // [256,128]
                           const float* __restrict__ b1,  // [256]
                           const float* __restrict__ W2,  // [128,256]
                           const float* __restrict__ b2,  // [128]
                           float* __restrict__ out) {     // [NB,128]
    int b = blockIdx.x;
    __shared__ float qs[128];
    __shared__ float hid[256];
    int tid = threadIdx.x;
    if (tid < 64) {
        qs[tid] = h[b * 64 + tid];
    } else if (tid < 128) {
        int k = tid - 64;
        float m0 = pm[b * SPLIT + 0], m1 = pm[b * SPLIT + 1];
        float m2 = pm[b * SPLIT + 2], m3 = pm[b * SPLIT + 3];
        float M = fmaxf(fmaxf(m0, m1), fmaxf(m2, m3));
        float w0 = __expf(m0 - M), w1 = __expf(m1 - M);
        float w2 = __expf(m2 - M), w3 = __expf(m3 - M);
        float S = ps[b * SPLIT + 0] * w0 + ps[b * SPLIT + 1] * w1
                + ps[b * SPLIT + 2] * w2 + ps[b * SPLIT + 3] * w3;
        float rf = pr[(b * SPLIT + 0) * 64 + k] * w0
                 + pr[(b * SPLIT + 1) * 64 + k] * w1
                 + pr[(b * SPLIT + 2) * 64 + k] * w2
                 + pr[(b * SPLIT + 3) * 64 + k] * w3;
        qs[tid] = rf / fmaxf(S, 1e-16f);
    }
    __syncthreads();
    float acc = b1[tid];
    const float4* w = (const float4*)(W1 + tid * 128);
#pragma unroll 4
    for (int k4 = 0; k4 < 32; ++k4) {
        float4 ww = w[k4];
        acc = fmaf(ww.x, qs[k4 * 4 + 0], acc);
        acc = fmaf(ww.y, qs[k4 * 4 + 1], acc);
        acc = fmaf(ww.z, qs[k4 * 4 + 2], acc);
        acc = fmaf(ww.w, qs[k4 * 4 + 3], acc);
    }
    hid[tid] = fmaxf(acc, 0.0f);
    __syncthreads();
    if (tid < 128) {
        float acc2 = b2[tid];
        const float4* w2 = (const float4*)(W2 + tid * 256);
#pragma unroll 4
        for (int k4 = 0; k4 < 64; ++k4) {
            float4 ww = w2[k4];
            acc2 = fmaf(ww.x, hid[k4 * 4 + 0], acc2);
            acc2 = fmaf(ww.y, hid[k4 * 4 + 1], acc2);
            acc2 = fmaf(ww.z, hid[k4 * 4 + 2], acc2);
            acc2 = fmaf(ww.w, hid[k4 * 4 + 3], acc2);
        }
        out[b * 128 + tid] = acc2;
    }
}

extern "C" void kernel_launch(void* const* d_in, const int* in_sizes, int n_in,
                              void* d_out, int out_size, void* d_ws, size_t ws_size,
                              hipStream_t stream) {
    const float* x    = (const float*)d_in[0];   // [N,64]
    const int*   batch= (const int*)d_in[1];     // [N] sorted
    const float* W_ih = (const float*)d_in[2];   // [256,128]
    const float* W_hh = (const float*)d_in[3];   // [256,64]
    const float* b_ih = (const float*)d_in[4];
    const float* b_hh = (const float*)d_in[5];
    const float* W1   = (const float*)d_in[6];   // [256,128]
    const float* b1   = (const float*)d_in[7];
    const float* W2   = (const float*)d_in[8];   // [128,256]
    const float* b2   = (const float*)d_in[9];
    float* out = (float*)d_out;
    const int N = in_sizes[1];

    // workspace layout
    float* h   = (float*)d_ws;                   // NB*64
    float* c   = h + NB * 64;                    // NB*64
    int*   seg = (int*)(c + NB * 64);            // NB+8 (padded)
    float* pm  = (float*)(seg + NB + 8);         // NB*SPLIT
    float* ps  = pm + NB * SPLIT;                // NB*SPLIT
    float* pr  = ps + NB * SPLIT;                // NB*SPLIT*64

    seg_bounds_kernel<<<(N + 255) / 256, 256, 0, stream>>>(batch, seg, N);

    for (int step = 0; step < NSTEPS; ++step) {
        lstm_kernel<<<NB / 8, 256, 0, stream>>>(W_ih, W_hh, b_ih, b_hh,
                                                pm, ps, pr, h, c, step == 0 ? 1 : 0);
        attn_kernel<<<NB * SPLIT, 256, 0, stream>>>(x, seg, h, pm, ps, pr);
    }
    mlp_kernel<<<NB, 256, 0, stream>>>(h, pm, ps, pr, W1, b1, W2, b2, out);
}

// Round 3
// 614.561 us; speedup vs baseline: 1.0296x; 1.0070x over previous
//
#include <hip/hip_runtime.h>
#include <float.h>
#include <math.h>

// Problem constants (fixed by the reference)
#define NB 1024      // number of graphs B
#define HD 64        // feature dim H
#define NSTEPS 5
#define SPLIT 4      // blocks per graph segment in attention

__device__ __forceinline__ float sigmoidf_(float x) {
    return 1.0f / (1.0f + __expf(-x));
}

// ---------------- segment boundaries from sorted batch ----------------
__global__ void seg_bounds_kernel(const int* __restrict__ batch,
                                  int* __restrict__ seg_start, int n) {
    int i = blockIdx.x * blockDim.x + threadIdx.x;
    if (i >= n) return;
    int b = batch[i];
    if (i == 0) {
        for (int j = 0; j <= b; ++j) seg_start[j] = 0;
    } else {
        int pb = batch[i - 1];
        for (int j = pb + 1; j <= b; ++j) seg_start[j] = i;
    }
    if (i == n - 1) {
        for (int j = b + 1; j <= NB; ++j) seg_start[j] = n;
    }
}

// ---------------- LSTM cell, fused with merge of previous step's attention partials ----------------
__global__ void lstm_kernel(const float* __restrict__ W_ih,  // [256,128]
                            const float* __restrict__ W_hh,  // [256,64]
                            const float* __restrict__ b_ih,  // [256]
                            const float* __restrict__ b_hh,  // [256]
                            const float* __restrict__ pm,    // [NB*SPLIT]
                            const float* __restrict__ ps,    // [NB*SPLIT]
                            const float* __restrict__ pr,    // [NB*SPLIT,64]
                            float* __restrict__ h,           // [NB,64]
                            float* __restrict__ c,           // [NB,64]
                            int first) {
    const int G = 8;
    int g0 = blockIdx.x * G;
    __shared__ float s_qs[G][128];    // [h_prev | r_prev]
    __shared__ float s_gates[G][256];
    int tid = threadIdx.x;

    if (!first) {
        for (int idx = tid; idx < G * 64; idx += 256) {
            int g = idx >> 6, k = idx & 63;
            s_qs[g][k] = h[(g0 + g) * 64 + k];
        }
        for (int idx = tid; idx < G * 64; idx += 256) {
            int g = idx >> 6, k = idx & 63;
            int b = g0 + g;
            float m0 = pm[b * SPLIT + 0], m1 = pm[b * SPLIT + 1];
            float m2 = pm[b * SPLIT + 2], m3 = pm[b * SPLIT + 3];
            float M = fmaxf(fmaxf(m0, m1), fmaxf(m2, m3));
            float w0 = __expf(m0 - M), w1 = __expf(m1 - M);
            float w2 = __expf(m2 - M), w3 = __expf(m3 - M);
            float S = ps[b * SPLIT + 0] * w0 + ps[b * SPLIT + 1] * w1
                    + ps[b * SPLIT + 2] * w2 + ps[b * SPLIT + 3] * w3;
            float rf = pr[(b * SPLIT + 0) * 64 + k] * w0
                     + pr[(b * SPLIT + 1) * 64 + k] * w1
                     + pr[(b * SPLIT + 2) * 64 + k] * w2
                     + pr[(b * SPLIT + 3) * 64 + k] * w3;
            s_qs[g][64 + k] = rf / fmaxf(S, 1e-16f);
        }
        __syncthreads();
    }

    int j = tid;  // gate row 0..255
    float acc[G];
    float bias = b_ih[j] + b_hh[j];
#pragma unroll
    for (int g = 0; g < G; ++g) acc[g] = bias;

    if (!first) {
        const float4* wih = (const float4*)(W_ih + j * 128);
#pragma unroll 4
        for (int k4 = 0; k4 < 32; ++k4) {
            float4 w = wih[k4];
#pragma unroll
            for (int g = 0; g < G; ++g) {
                acc[g] = fmaf(w.x, s_qs[g][k4 * 4 + 0], acc[g]);
                acc[g] = fmaf(w.y, s_qs[g][k4 * 4 + 1], acc[g]);
                acc[g] = fmaf(w.z, s_qs[g][k4 * 4 + 2], acc[g]);
                acc[g] = fmaf(w.w, s_qs[g][k4 * 4 + 3], acc[g]);
            }
        }
        const float4* whh = (const float4*)(W_hh + j * 64);
#pragma unroll 4
        for (int k4 = 0; k4 < 16; ++k4) {
            float4 w = whh[k4];
#pragma unroll
            for (int g = 0; g < G; ++g) {
                acc[g] = fmaf(w.x, s_qs[g][k4 * 4 + 0], acc[g]);
                acc[g] = fmaf(w.y, s_qs[g][k4 * 4 + 1], acc[g]);
                acc[g] = fmaf(w.z, s_qs[g][k4 * 4 + 2], acc[g]);
                acc[g] = fmaf(w.w, s_qs[g][k4 * 4 + 3], acc[g]);
            }
        }
    }
#pragma unroll
    for (int g = 0; g < G; ++g) s_gates[g][j] = acc[g];
    __syncthreads();

    for (int idx = tid; idx < G * 64; idx += 256) {
        int g = idx >> 6, jj = idx & 63;
        int gb = g0 + g;
        float ig = sigmoidf_(s_gates[g][jj]);
        float fg = sigmoidf_(s_gates[g][jj + 64]);
        float gg = tanhf(s_gates[g][jj + 128]);
        float og = sigmoidf_(s_gates[g][jj + 192]);
        float cprev = first ? 0.0f : c[gb * 64 + jj];
        float cn = fmaf(fg, cprev, ig * gg);
        float hn = og * tanhf(cn);
        c[gb * 64 + jj] = cn;
        h[gb * 64 + jj] = hn;
    }
}

// ---------------- fused segment attention (online softmax, single pass) ----------------
// grid = NB*SPLIT blocks. 256 threads = 4 waves; wave handles 16 nodes per iter.
// COALESCED: every global load instruction covers 1 KB contiguous (64 lanes x float4).
// Lane l owns feature chunk (l&15)*4..+4 of node t*4 + (l>>4).
__global__ __launch_bounds__(256) void attn_kernel(const float* __restrict__ x,
                                                   const int* __restrict__ seg_start,
                                                   const float* __restrict__ h,
                                                   float* __restrict__ pm,
                                                   float* __restrict__ ps,
                                                   float* __restrict__ pr) {
    int bs = blockIdx.x;
    int b = bs >> 2;            // SPLIT == 4
    int slice = bs & (SPLIT - 1);
    int s0 = seg_start[b], e0 = seg_start[b + 1];
    int len = e0 - s0;
    int s = s0 + (int)(((long long)len * slice) >> 2);
    int e = s0 + (int)(((long long)len * (slice + 1)) >> 2);

    int tid = threadIdx.x;
    int lane = tid & 63;
    int wave = tid >> 6;      // 0..3
    int fc = lane & 15;       // feature chunk (4 floats)
    int grp = lane >> 4;      // node subgroup 0..3

    // q chunk for this lane: floats [fc*4, fc*4+4) of h[b]
    float4 q4 = *(const float4*)(h + b * 64 + fc * 4);

    float m = -FLT_MAX, sum = 0.0f;
    float4 r4 = make_float4(0.0f, 0.0f, 0.0f, 0.0f);

    const int maxidx4 = e * 16 - 1;   // clamp for partial tiles
    for (int base = s + wave * 16; base < e; base += 64) {
#pragma unroll
        for (int t = 0; t < 4; ++t) {
            int node = base + t * 4 + grp;
            int idx4 = base * 16 + t * 64 + lane;   // global float4 index (contiguous per instr)
            idx4 = min(idx4, maxidx4);
            float4 xv = *(const float4*)(x + (size_t)idx4 * 4);

            float d = xv.x * q4.x;
            d = fmaf(xv.y, q4.y, d);
            d = fmaf(xv.z, q4.z, d);
            d = fmaf(xv.w, q4.w, d);
            // reduce over the 16-lane group (all lanes of group share node)
            d += __shfl_xor(d, 1);
            d += __shfl_xor(d, 2);
            d += __shfl_xor(d, 4);
            d += __shfl_xor(d, 8);

            bool valid = node < e;
            float eeff = valid ? d : -FLT_MAX;
            float nm = fmaxf(m, eeff);
            float sc = __expf(m - nm);          // ==1 when m==nm (incl. both -FLT_MAX)
            float w = valid ? __expf(eeff - nm) : 0.0f;
            sum = fmaf(sum, sc, w);
            r4.x = fmaf(r4.x, sc, w * xv.x);
            r4.y = fmaf(r4.y, sc, w * xv.y);
            r4.z = fmaf(r4.z, sc, w * xv.z);
            r4.w = fmaf(r4.w, sc, w * xv.w);
            m = nm;
        }
    }

    // merge across the 4 node-subgroups (lanes with equal fc hold same feature chunk)
#pragma unroll
    for (int off = 16; off < 64; off <<= 1) {
        float om = __shfl_xor(m, off);
        float os = __shfl_xor(sum, off);
        float ox = __shfl_xor(r4.x, off);
        float oy = __shfl_xor(r4.y, off);
        float oz = __shfl_xor(r4.z, off);
        float ow = __shfl_xor(r4.w, off);
        float nm = fmaxf(m, om);
        float s1 = __expf(m - nm);
        float s2 = __expf(om - nm);
        sum = sum * s1 + os * s2;
        r4.x = r4.x * s1 + ox * s2;
        r4.y = r4.y * s1 + oy * s2;
        r4.z = r4.z * s1 + oz * s2;
        r4.w = r4.w * s1 + ow * s2;
        m = nm;
    }

    // cross-wave merge via LDS; write UNNORMALIZED partials
    __shared__ float lm[4], ls[4], lr[4][64];
    if (lane < 16) {
        if (lane == 0) { lm[wave] = m; ls[wave] = sum; }
        *(float4*)&lr[wave][lane * 4] = r4;
    }
    __syncthreads();
    if (tid < 64) {
        float M = fmaxf(fmaxf(lm[0], lm[1]), fmaxf(lm[2], lm[3]));
        float w0 = __expf(lm[0] - M), w1 = __expf(lm[1] - M);
        float w2 = __expf(lm[2] - M), w3 = __expf(lm[3] - M);
        float S = ls[0] * w0 + ls[1] * w1 + ls[2] * w2 + ls[3] * w3;
        float rf = lr[0][tid] * w0 + lr[1][tid] * w1 + lr[2][tid] * w2 + lr[3][tid] * w3;
        if (tid == 0) { pm[bs] = M; ps[bs] = S; }
        pr[bs * 64 + tid] = rf;
    }
}

// ---------------- final: merge last partials, build q_star, MLP ----------------
__global__ void mlp_kernel(const float* __restrict__ h,
                           const float* __restrict__ pm,
                           const float* __restrict__ ps,
                           const float* __restrict__ pr,
                           const float* __restrict__ W1,  // [256,128]
                           const float* __restrict__ b1,  // [256]
                           const float* __restrict__ W2,  // [128,256]
                           const float* __restrict__ b2,  // [128]
                           float* __restrict__ out) {     // [NB,128]
    int b = blockIdx.x;
    __shared__ float qs[128];
    __shared__ float hid[256];
    int tid = threadIdx.x;
    if (tid < 64) {
        qs[tid] = h[b * 64 + tid];
    } else if (tid < 128) {
        int k = tid - 64;
        float m0 = pm[b * SPLIT + 0], m1 = pm[b * SPLIT + 1];
        float m2 = pm[b * SPLIT + 2], m3 = pm[b * SPLIT + 3];
        float M = fmaxf(fmaxf(m0, m1), fmaxf(m2, m3));
        float w0 = __expf(m0 - M), w1 = __expf(m1 - M);
        float w2 = __expf(m2 - M), w3 = __expf(m3 - M);
        float S = ps[b * SPLIT + 0] * w0 + ps[b * SPLIT + 1] * w1
                + ps[b * SPLIT + 2] * w2 + ps[b * SPLIT + 3] * w3;
        float rf = pr[(b * SPLIT + 0) * 64 + k] * w0
                 + pr[(b * SPLIT + 1) * 64 + k] * w1
                 + pr[(b * SPLIT + 2) * 64 + k] * w2
                 + pr[(b * SPLIT + 3) * 64 + k] * w3;
        qs[tid] = rf / fmaxf(S, 1e-16f);
    }
    __syncthreads();
    float acc = b1[tid];
    const float4* w = (const float4*)(W1 + tid * 128);
#pragma unroll 4
    for (int k4 = 0; k4 < 32; ++k4) {
        float4 ww = w[k4];
        acc = fmaf(ww.x, qs[k4 * 4 + 0], acc);
        acc = fmaf(ww.y, qs[k4 * 4 + 1], acc);
        acc = fmaf(ww.z, qs[k4 * 4 + 2], acc);
        acc = fmaf(ww.w, qs[k4 * 4 + 3], acc);
    }
    hid[tid] = fmaxf(acc, 0.0f);
    __syncthreads();
    if (tid < 128) {
        float acc2 = b2[tid];
        const float4* w2 = (const float4*)(W2 + tid * 256);
#pragma unroll 4
        for (int k4 = 0; k4 < 64; ++k4) {
            float4 ww = w2[k4];
            acc2 = fmaf(ww.x, hid[k4 * 4 + 0], acc2);
            acc2 = fmaf(ww.y, hid[k4 * 4 + 1], acc2);
            acc2 = fmaf(ww.z, hid[k4 * 4 + 2], acc2);
            acc2 = fmaf(ww.w, hid[k4 * 4 + 3], acc2);
        }
        out[b * 128 + tid] = acc2;
    }
}

extern "C" void kernel_launch(void* const* d_in, const int* in_sizes, int n_in,
                              void* d_out, int out_size, void* d_ws, size_t ws_size,
                              hipStream_t stream) {
    const float* x    = (const float*)d_in[0];   // [N,64]
    const int*   batch= (const int*)d_in[1];     // [N] sorted
    const float* W_ih = (const float*)d_in[2];   // [256,128]
    const float* W_hh = (const float*)d_in[3];   // [256,64]
    const float* b_ih = (const float*)d_in[4];
    const float* b_hh = (const float*)d_in[5];
    const float* W1   = (const float*)d_in[6];   // [256,128]
    const float* b1   = (const float*)d_in[7];
    const float* W2   = (const float*)d_in[8];   // [128,256]
    const float* b2   = (const float*)d_in[9];
    float* out = (float*)d_out;
    const int N = in_sizes[1];

    // workspace layout
    float* h   = (float*)d_ws;                   // NB*64
    float* c   = h + NB * 64;                    // NB*64
    int*   seg = (int*)(c + NB * 64);            // NB+8 (padded)
    float* pm  = (float*)(seg + NB + 8);         // NB*SPLIT
    float* ps  = pm + NB * SPLIT;                // NB*SPLIT
    float* pr  = ps + NB * SPLIT;                // NB*SPLIT*64

    seg_bounds_kernel<<<(N + 255) / 256, 256, 0, stream>>>(batch, seg, N);

    for (int step = 0; step < NSTEPS; ++step) {
        lstm_kernel<<<NB / 8, 256, 0, stream>>>(W_ih, W_hh, b_ih, b_hh,
                                                pm, ps, pr, h, c, step == 0 ? 1 : 0);
        attn_kernel<<<NB * SPLIT, 256, 0, stream>>>(x, seg, h, pm, ps, pr);
    }
    mlp_kernel<<<NB, 256, 0, stream>>>(h, pm, ps, pr, W1, b1, W2, b2, out);
}